// Round 3
// baseline (92.750 us; speedup 1.0000x reference)
//
#include <hip/hip_runtime.h>
#include <math.h>

#define N 4096
#define FEPS 1e-7f
#define ROWS 4
#define BLK 256

// Single self-contained kernel: no workspace, no precompute pass.
// Each block owns ROWS=4 output rows; thread t strides j = t, t+BLK, ...
// computing the j-box features inline (registers only), applying them to all
// 4 rows, then a wave-shuffle + LDS block reduction and fused epilogue.
//
// NaN guard: fast v_rcp_f32 can make iou land 1 ulp ABOVE 1.0; on diagonal
// pairs (v == 0) the alpha denominator v - iou + (1+eps) then cancels to
// exactly 0.0 and alpha = 0 * inf = NaN. fminf(iou, 1.0f) restores the
// reference's invariant iou <= 1 (denominator >= 1.19e-7 > 0 always).
__global__ __launch_bounds__(BLK) void ciou_attn_kernel(
        const float* __restrict__ x,
        const float* __restrict__ gamma,
        float* __restrict__ out) {
    const int tid = threadIdx.x;
    const int i0 = blockIdx.x * ROWS;

    // Per-row (query box) features — uniform addresses, scalar-cached.
    float rx1[ROWS], ry1[ROWS], rx2[ROWS], ry2[ROWS];
    float rsx[ROWS], rsy[ROWS], rar[ROWS], rat[ROWS], rcf[ROWS];
#pragma unroll
    for (int r = 0; r < ROWS; r++) {
        const float* xi = x + (size_t)(i0 + r) * 5;
        float cf = xi[0], x1 = xi[1], y1 = xi[2], x2 = xi[3], y2 = xi[4];
        float w = x2 - x1, h = y2 - y1;
        rcf[r] = cf;
        rx1[r] = x1; ry1[r] = y1; rx2[r] = x2; ry2[r] = y2;
        rsx[r] = x1 + x2; rsy[r] = y1 + y2;
        rar[r] = w * h;
        rat[r] = atanf(w / (h + FEPS));
    }

    float sum[ROWS];
    float acc[ROWS][5];
#pragma unroll
    for (int r = 0; r < ROWS; r++) {
        sum[r] = 0.f;
#pragma unroll
        for (int c = 0; c < 5; c++) acc[r][c] = 0.f;
    }

    const float K = 0.4052847345693511f;  // 4/pi^2

    for (int j = tid; j < N; j += BLK) {
        const float* xj = x + (size_t)j * 5;
        float jcf = xj[0], jx1 = xj[1], jy1 = xj[2], jx2 = xj[3], jy2 = xj[4];
        float jw = jx2 - jx1, jh = jy2 - jy1;
        float jsx = jx1 + jx2, jsy = jy1 + jy2;
        float jar = jw * jh;
        float jat = atanf(jw / (jh + FEPS));
#pragma unroll
        for (int r = 0; r < ROWS; r++) {
            float iw = fminf(rx2[r], jx2) - fmaxf(rx1[r], jx1);
            iw = fmaxf(iw, 0.f);
            float ih = fminf(ry2[r], jy2) - fmaxf(ry1[r], jy1);
            ih = fmaxf(ih, 0.f);
            float inter = iw * ih;
            float uni = rar[r] + jar - inter + FEPS;
            float iou = inter * __builtin_amdgcn_rcpf(uni);
            iou = fminf(iou, 1.0f);  // NaN guard — see header comment
            float cw = fmaxf(rx2[r], jx2) - fminf(rx1[r], jx1);
            float ch = fmaxf(ry2[r], jy2) - fminf(ry1[r], jy1);
            float c2 = cw * cw + ch * ch + FEPS;
            float dx = jsx - rsx[r];
            float dy = jsy - rsy[r];
            float rho2 = (dx * dx + dy * dy) * 0.25f;
            float da = jat - rat[r];
            float v = K * da * da;
            float alpha = v * __builtin_amdgcn_rcpf(v - iou + (1.f + FEPS));
            float ciou = iou - (rho2 * __builtin_amdgcn_rcpf(c2) + v * alpha);
            float s = ciou * rcf[r] * jcf;
            float e = __expf(s);  // s in (-3, 1] — no max-subtraction needed
            sum[r] += e;
            acc[r][0] += e * jcf;
            acc[r][1] += e * jx1;
            acc[r][2] += e * jy1;
            acc[r][3] += e * jx2;
            acc[r][4] += e * jy2;
        }
    }

    // Wave shuffle reduction (width 64) then cross-wave via LDS.
    __shared__ float red[BLK / 64][ROWS * 6];
    const int wave = tid >> 6;
    const int lane = tid & 63;
#pragma unroll
    for (int r = 0; r < ROWS; r++) {
        float v6[6] = {sum[r], acc[r][0], acc[r][1], acc[r][2], acc[r][3], acc[r][4]};
#pragma unroll
        for (int k = 0; k < 6; k++) {
            float val = v6[k];
#pragma unroll
            for (int off = 32; off > 0; off >>= 1) val += __shfl_down(val, off, 64);
            if (lane == 0) red[wave][r * 6 + k] = val;
        }
    }
    __syncthreads();
    if (tid < ROWS * 6) {
        float tot = 0.f;
#pragma unroll
        for (int w = 0; w < BLK / 64; w++) tot += red[w][tid];
        red[0][tid] = tot;
    }
    __syncthreads();
    if (tid < ROWS * 5) {
        int r = tid / 5, c = tid % 5;
        int i = i0 + r;
        float se = red[0][r * 6];
        float a = red[0][r * 6 + 1 + c];
        float xp = x[(size_t)i * 5 + c] * gamma[0] + a / se;
        out[(size_t)i * 5 + c] = 1.f / (1.f + expf(-xp));
    }
}

extern "C" void kernel_launch(void* const* d_in, const int* in_sizes, int n_in,
                              void* d_out, int out_size, void* d_ws, size_t ws_size,
                              hipStream_t stream) {
    const float* x = (const float*)d_in[0];
    const float* gamma = (const float*)d_in[1];
    float* out = (float*)d_out;
    ciou_attn_kernel<<<N / ROWS, BLK, 0, stream>>>(x, gamma, out);
}

// Round 4
// 92.269 us; speedup vs baseline: 1.0052x; 1.0052x over previous
//
#include <hip/hip_runtime.h>
#include <math.h>

#define N 4096
#define FEPS 1e-7f
#define ROWS 8
#define BLK 256
#define FSTRIDE 12  // per-box feature record, padded to 48 B for float4 loads

// Feature record per box j (f[j*12 + k]):
// 0:conf 1:x1 2:y1 3:x2 4:y2 5:x1+x2 6:y1+y2 7:w 8:h 9:area+eps 10:atan(w/(h+eps)) 11:area
__global__ void precompute_kernel(const float* __restrict__ x, float* __restrict__ f) {
    int i = blockIdx.x * blockDim.x + threadIdx.x;
    if (i >= N) return;
    float cf = x[i * 5 + 0], x1 = x[i * 5 + 1], y1 = x[i * 5 + 2];
    float x2 = x[i * 5 + 3], y2 = x[i * 5 + 4];
    float w = x2 - x1, h = y2 - y1;
    float* fi = f + (size_t)i * FSTRIDE;
    fi[0] = cf; fi[1] = x1; fi[2] = y1; fi[3] = x2; fi[4] = y2;
    fi[5] = x1 + x2; fi[6] = y1 + y2; fi[7] = w; fi[8] = h;
    fi[9] = w * h + FEPS;             // area + eps (folded into union)
    fi[10] = atanf(w / (h + FEPS));   // hoisted out of the N^2 loop
    fi[11] = w * h;                   // raw area
}

// Each block owns ROWS=8 rows; thread t strides j = t, t+BLK, ...
// cw/ch use the identity max(a2,b2)-min(a1,b1) = w1+w2-(min(a2,b2)-max(a1,b1)).
// iou clamped to 1.0 (fast-rcp 1-ulp overshoot makes the alpha denominator
// cancel to exactly 0 on diagonal pairs otherwise -> NaN).
__global__ __launch_bounds__(BLK) void ciou_attn_kernel(
        const float* __restrict__ x,
        const float* __restrict__ f,
        const float* __restrict__ gamma,
        float* __restrict__ out) {
    const int tid = threadIdx.x;
    const int i0 = blockIdx.x * ROWS;

    float rx1[ROWS], ry1[ROWS], rx2[ROWS], ry2[ROWS], rsx[ROWS], rsy[ROWS];
    float rw[ROWS], rh[ROWS], rar[ROWS], rat[ROWS], rcf[ROWS];
#pragma unroll
    for (int r = 0; r < ROWS; r++) {
        const float* fi = f + (size_t)(i0 + r) * FSTRIDE;
        rcf[r] = fi[0]; rx1[r] = fi[1]; ry1[r] = fi[2]; rx2[r] = fi[3]; ry2[r] = fi[4];
        rsx[r] = fi[5]; rsy[r] = fi[6]; rw[r] = fi[7]; rh[r] = fi[8];
        rar[r] = fi[11]; rat[r] = fi[10];
    }

    float sum[ROWS];
    float acc[ROWS][5];
#pragma unroll
    for (int r = 0; r < ROWS; r++) {
        sum[r] = 0.f;
#pragma unroll
        for (int c = 0; c < 5; c++) acc[r][c] = 0.f;
    }

    const float K = 0.4052847345693511f;  // 4/pi^2
    const float ONEP = 1.f + FEPS;

#pragma unroll 2
    for (int j = tid; j < N; j += BLK) {
        const float4* fj = (const float4*)(f + (size_t)j * FSTRIDE);
        float4 A = fj[0], B = fj[1], C = fj[2];
        float jcf = A.x, jx1 = A.y, jy1 = A.z, jx2 = A.w;
        float jy2 = B.x, jsx = B.y, jsy = B.z, jw = B.w;
        float jh = C.x, jar2 = C.y, jat = C.z;
#pragma unroll
        for (int r = 0; r < ROWS; r++) {
            float iwr = fminf(rx2[r], jx2) - fmaxf(rx1[r], jx1);
            float ihr = fminf(ry2[r], jy2) - fmaxf(ry1[r], jy1);
            float iw = fmaxf(iwr, 0.f);
            float ih = fmaxf(ihr, 0.f);
            float inter = iw * ih;
            float uni = (rar[r] + jar2) - inter;  // jar2 = area_j + eps
            float iou = fminf(inter * __builtin_amdgcn_rcpf(uni), 1.0f);
            float cw = (rw[r] + jw) - iwr;  // enclosing width via identity
            float ch = (rh[r] + jh) - ihr;
            float c2 = cw * cw + ch * ch + FEPS;
            float dx = jsx - rsx[r];
            float dy = jsy - rsy[r];
            float rho2 = (dx * dx + dy * dy) * 0.25f;
            float da = jat - rat[r];
            float v = K * da * da;
            float den = (v - iou) + ONEP;
            float valpha = v * v * __builtin_amdgcn_rcpf(den);  // v * alpha
            float ciou = iou - (rho2 * __builtin_amdgcn_rcpf(c2) + valpha);
            float e = __expf(ciou * rcf[r] * jcf);  // score in (-3,1]: no max-sub
            sum[r] += e;
            acc[r][0] += e * jcf;
            acc[r][1] += e * jx1;
            acc[r][2] += e * jy1;
            acc[r][3] += e * jx2;
            acc[r][4] += e * jy2;
        }
    }

    // Wave shuffle reduction (width 64) then cross-wave via LDS.
    __shared__ float red[BLK / 64][ROWS * 6];
    const int wave = tid >> 6;
    const int lane = tid & 63;
#pragma unroll
    for (int r = 0; r < ROWS; r++) {
        float v6[6] = {sum[r], acc[r][0], acc[r][1], acc[r][2], acc[r][3], acc[r][4]};
#pragma unroll
        for (int k = 0; k < 6; k++) {
            float val = v6[k];
#pragma unroll
            for (int off = 32; off > 0; off >>= 1) val += __shfl_down(val, off, 64);
            if (lane == 0) red[wave][r * 6 + k] = val;
        }
    }
    __syncthreads();
    if (tid < ROWS * 6) {
        float tot = 0.f;
#pragma unroll
        for (int w = 0; w < BLK / 64; w++) tot += red[w][tid];
        red[0][tid] = tot;
    }
    __syncthreads();
    if (tid < ROWS * 5) {
        int r = tid / 5, c = tid % 5;
        int i = i0 + r;
        float se = red[0][r * 6];
        float a = red[0][r * 6 + 1 + c];
        float xp = x[(size_t)i * 5 + c] * gamma[0] + a / se;
        out[(size_t)i * 5 + c] = 1.f / (1.f + expf(-xp));
    }
}

extern "C" void kernel_launch(void* const* d_in, const int* in_sizes, int n_in,
                              void* d_out, int out_size, void* d_ws, size_t ws_size,
                              hipStream_t stream) {
    const float* x = (const float*)d_in[0];
    const float* gamma = (const float*)d_in[1];
    float* out = (float*)d_out;
    float* f = (float*)d_ws;  // N*12 floats = 196608 B; fully rewritten every call

    precompute_kernel<<<(N + 255) / 256, 256, 0, stream>>>(x, f);
    ciou_attn_kernel<<<N / ROWS, BLK, 0, stream>>>(x, f, gamma, out);
}